// Round 12
// baseline (34402.350 us; speedup 1.0000x reference)
//
#include <hip/hip_runtime.h>
#include <stdint.h>

#define Ic 128   // input size
#define Hc 256   // hidden size

typedef uint32_t u32;
typedef unsigned long long u64;
typedef uint32_t u32x2v __attribute__((ext_vector_type(2)));
using half2v = __attribute__((ext_vector_type(2))) _Float16;

__device__ __forceinline__ u32 pk_rne(float a, float b) {
    _Float16 lo = (_Float16)a, hi = (_Float16)b;
    return (u32)__builtin_bit_cast(uint16_t, lo) |
           ((u32)__builtin_bit_cast(uint16_t, hi) << 16);
}
__device__ __forceinline__ float dot2acc(u32 a, u32 b, float c) {
    return __builtin_amdgcn_fdot2(__builtin_bit_cast(half2v, a),
                                  __builtin_bit_cast(half2v, b), c, false);
}
__device__ __forceinline__ u32 rl(u32 v, int k) {
    return (u32)__builtin_amdgcn_readlane((int)v, k);
}
__device__ __forceinline__ float sigm(float x) {
    return __builtin_amdgcn_rcpf(1.f + __expf(-x));
}
__device__ __forceinline__ float tanh_f(float x) {
    float e = __expf(-2.f * __builtin_fabsf(x));
    float t = (1.f - e) * __builtin_amdgcn_rcpf(1.f + e);
    return __builtin_copysignf(t, x);
}

// ---- tagged-slot exchange, same-XCD L2 fast path ----
// Slot = one u64: {payload(lo dword), tag(hi dword)} — single 8B transaction.
// Publish: WRITE-THROUGH store (sc0 sc1) -> shared XCD L2 updated + MALL truth;
// L2 never holds dirty exchange lines, so invalidations are always safe.
// Poll: alternate L2 probe (sc0: fast if pair-mate shares the XCD L2) and MALL
// probe (sc0 sc1: correctness under ANY block->XCD mapping; a stale L2 line can
// delay detection by at most one iteration, never deadlock).
__device__ __forceinline__ u32x2v ld64_l2(const void* p) {
    u32x2v r;
    asm volatile("global_load_dwordx2 %0, %1, off sc0\n\ts_waitcnt vmcnt(0)"
                 : "=v"(r) : "v"(p) : "memory");
    return r;
}
__device__ __forceinline__ u32x2v ld64_mall(const void* p) {
    u32x2v r;
    asm volatile("global_load_dwordx2 %0, %1, off sc0 sc1\n\ts_waitcnt vmcnt(0)"
                 : "=v"(r) : "v"(p) : "memory");
    return r;
}
__device__ __forceinline__ void st64_wt(void* p, u32 lo, u32 hi) {
    u32x2v v; v[0] = lo; v[1] = hi;
    asm volatile("global_store_dwordx2 %0, %1, off sc0 sc1" :: "v"(p), "v"(v) : "memory");
}
__device__ __forceinline__ void st32_wt(float* p, float v) {
    asm volatile("global_store_dword %0, %1, off sc0 sc1" :: "v"(p), "v"(v) : "memory");
}
// Kernel-entry L2 invalidate (compiler-emitted via agent-scope acquire):
// kills stale exchange lines left in this XCD's L2 by the previous graph replay.
__device__ __forceinline__ void inv_caches(const void* p) {
    (void)__hip_atomic_load((const u32*)p, __ATOMIC_ACQUIRE, __HIP_MEMORY_SCOPE_AGENT);
}
// Raw barrier: LDS-ordering only (no vmcnt drain).
__device__ __forceinline__ void block_sync_lds() {
    asm volatile("s_waitcnt lgkmcnt(0)" ::: "memory");
    __builtin_amdgcn_sched_barrier(0);
    __builtin_amdgcn_s_barrier();
    __builtin_amdgcn_sched_barrier(0);
}

// ===================== Encoder =====================
// 256 blocks of 256 threads (1 wave/SIMD, full 512-reg budget). Pair p =
// (dir,batch); half k owns units [k*128,+128). Wave w owns ALL 4 gates of its
// 32 units; cell = 2 intra-wave shfls; each wave publishes its 16 h-pair slots
// as soon as its dots finish. ONE raw barrier/step. x in registers, 1 ahead.
__global__ __launch_bounds__(256, 1) void enc_kernel(
    const float* __restrict__ x,
    const float* __restrict__ WihF, const float* __restrict__ WhhF,
    const float* __restrict__ bihF, const float* __restrict__ bhhF,
    const float* __restrict__ WihB, const float* __restrict__ WhhB,
    const float* __restrict__ bihB, const float* __restrict__ bhhB,
    float* __restrict__ hF, float* __restrict__ hB,
    u64* __restrict__ xch,    // [128 pairs][2 halves][2 parity][64]
    int T)
{
    const int t    = threadIdx.x;
    const int lane = t & 63;
    const int w    = t >> 6;
    const int j    = lane & 31;
    const int sel  = lane >> 5;                  // 0: rows (i,g), 1: rows (f,o)
    const int g    = blockIdx.x;
    const int half = (g >> 3) & 1;               // pair-mates g and g^8
    const int p    = ((g >> 4) << 3) | (g & 7);  // pair id 0..127
    const int rev  = p >> 6;
    const int b    = p & 63;

    inv_caches(xch);   // drop stale L2 exchange lines from previous replay

    const int u  = half * 128 + w * 32 + j;      // global hidden unit
    const int rA = sel * Hc + u;                 // gate 0(i) or 1(f)
    const int rB = (sel + 2) * Hc + u;           // gate 2(g) or 3(o)

    const float* Wih = rev ? WihB : WihF;
    const float* Whh = rev ? WhhB : WhhF;
    const float* bih = rev ? bihB : bihF;
    const float* bhh = rev ? bhhB : bhhF;

    __shared__ u32 s_zh[2][64];   // own-half h pairs, parity double-buffered

    u32 whAo[64], whAp[64], wiA[64];
    u32 whBo[64], whBp[64], wiB[64];
    {
        const int ob = half * 64, pb2 = (half ^ 1) * 64;
        const float* wrA = Whh + (size_t)rA * Hc;
        const float* wrB = Whh + (size_t)rB * Hc;
#pragma unroll
        for (int k = 0; k < 64; k++) {
            whAo[k] = pk_rne(wrA[2*(ob+k)],  wrA[2*(ob+k)+1]);
            whBo[k] = pk_rne(wrB[2*(ob+k)],  wrB[2*(ob+k)+1]);
            whAp[k] = pk_rne(wrA[2*(pb2+k)], wrA[2*(pb2+k)+1]);
            whBp[k] = pk_rne(wrB[2*(pb2+k)], wrB[2*(pb2+k)+1]);
        }
        const float* irA = Wih + (size_t)rA * Ic;
        const float* irB = Wih + (size_t)rB * Ic;
#pragma unroll
        for (int k = 0; k < 64; k++) {
            wiA[k] = pk_rne(irA[2*k], irA[2*k+1]);
            wiB[k] = pk_rne(irB[2*k], irB[2*k+1]);
        }
    }
    const float biasA = bih[rA] + bhh[rA];
    const float biasB = bih[rB] + bhh[rB];

    u64* xch_self = xch + ((size_t)(p * 2 + half)) * 128;        // 2 parity x 64
    u64* xch_peer = xch + ((size_t)(p * 2 + (half ^ 1))) * 128;

    if (t < 64) { s_zh[0][t] = 0u; s_zh[1][t] = 0u; }   // h0 = 0
    float2 xn;
    {   // preload x for step 0 (per-wave lane slice)
        int ts0 = rev ? (T - 1) : 0;
        xn = *(const float2*)(x + ((size_t)b * T + ts0) * Ic + 2 * lane);
    }
    __syncthreads();

    float c = 0.f;   // lanes j<32: cell of unit u
    for (int s = 0; s < T; s++) {
        u32 vzx = pk_rne(xn.x, xn.y);          // waited: load had a full iter
        int sn = s + 1;
        if (sn < T) {   // issue next x load (consumed at next iter head)
            int ts = rev ? (T - 1 - sn) : sn;
            xn = *(const float2*)(x + ((size_t)b * T + ts) * Ic + 2 * lane);
        }

        u32 vzo = s_zh[s & 1][lane];
        float aA0 = biasA, aA1 = 0.f, aA2 = 0.f, aA3 = 0.f;
        float aB0 = biasB, aB1 = 0.f, aB2 = 0.f, aB3 = 0.f;
#pragma unroll
        for (int k = 0; k < 64; k += 4) {
            u32 h0 = rl(vzx, k+0), h1 = rl(vzx, k+1), h2 = rl(vzx, k+2), h3 = rl(vzx, k+3);
            aA0 = dot2acc(h0, wiA[k+0], aA0); aB0 = dot2acc(h0, wiB[k+0], aB0);
            aA1 = dot2acc(h1, wiA[k+1], aA1); aB1 = dot2acc(h1, wiB[k+1], aB1);
            aA2 = dot2acc(h2, wiA[k+2], aA2); aB2 = dot2acc(h2, wiB[k+2], aB2);
            aA3 = dot2acc(h3, wiA[k+3], aA3); aB3 = dot2acc(h3, wiB[k+3], aB3);
        }
#pragma unroll
        for (int k = 0; k < 64; k += 4) {
            u32 h0 = rl(vzo, k+0), h1 = rl(vzo, k+1), h2 = rl(vzo, k+2), h3 = rl(vzo, k+3);
            aA0 = dot2acc(h0, whAo[k+0], aA0); aB0 = dot2acc(h0, whBo[k+0], aB0);
            aA1 = dot2acc(h1, whAo[k+1], aA1); aB1 = dot2acc(h1, whBo[k+1], aB1);
            aA2 = dot2acc(h2, whAo[k+2], aA2); aB2 = dot2acc(h2, whBo[k+2], aB2);
            aA3 = dot2acc(h3, whAo[k+3], aA3); aB3 = dot2acc(h3, whBo[k+3], aB3);
        }
        u32 vzp = 0u;
        if (s > 0) {   // per-lane spin: L2 probe / MALL probe alternation
            const u64* pslot = &xch_peer[(s & 1) * 64 + lane];
            u32x2v v = ld64_l2(pslot);
            int it = 0;
            while ((int)v[1] < s)
                v = ((++it) & 1) ? ld64_mall(pslot) : ld64_l2(pslot);
            vzp = v[0];
        }
#pragma unroll
        for (int k = 0; k < 64; k += 4) {
            u32 h0 = rl(vzp, k+0), h1 = rl(vzp, k+1), h2 = rl(vzp, k+2), h3 = rl(vzp, k+3);
            aA0 = dot2acc(h0, whAp[k+0], aA0); aB0 = dot2acc(h0, whBp[k+0], aB0);
            aA1 = dot2acc(h1, whAp[k+1], aA1); aB1 = dot2acc(h1, whBp[k+1], aB1);
            aA2 = dot2acc(h2, whAp[k+2], aA2); aB2 = dot2acc(h2, whBp[k+2], aB2);
            aA3 = dot2acc(h3, whAp[k+3], aA3); aB3 = dot2acc(h3, whBp[k+3], aB3);
        }
        float aAs = (aA0 + aA1) + (aA2 + aA3);   // lanes<32: i(u); lanes>=32: f(u)
        float aBs = (aB0 + aB1) + (aB2 + aB3);   // lanes<32: g(u); lanes>=32: o(u)

        // wave-local cell: fetch f,o from lane 32+j
        float f_ = __shfl(aAs, 32 + j);
        float o_ = __shfl(aBs, 32 + j);
        c = sigm(f_) * c + sigm(aAs) * tanh_f(aBs);
        float h = sigm(o_) * tanh_f(c);
        float he = __shfl(h, 2 * (lane & 15));
        float ho = __shfl(h, 2 * (lane & 15) + 1);
        u32 hp = pk_rne(he, ho);
        const int notlast = (s + 1 < T);
        if (lane < 16) {
            int q = w * 16 + lane;
            s_zh[(s + 1) & 1][q] = hp;
            if (notlast)
                st64_wt(&xch_self[((s + 1) & 1) * 64 + q], hp, (u32)(s + 1));
        }
        if (!notlast && lane < 32) {   // final h -> workspace
            (rev ? hB : hF)[(size_t)b * Hc + u] = h;
        }
        block_sync_lds();
    }
}

// ===================== Latent bottleneck =====================
__global__ void lat_kernel(const float* __restrict__ hF, const float* __restrict__ hB,
                           const float* __restrict__ latW, const float* __restrict__ latb,
                           const float* __restrict__ l2hW, const float* __restrict__ l2hb,
                           float* __restrict__ hidden)
{
    int b = blockIdx.x, t = threadIdx.x;  // 256 threads
    __shared__ float s_hn[512];
    __shared__ float s_lat[64];
    s_hn[t]       = hF[(size_t)b * Hc + t];
    s_hn[256 + t] = hB[(size_t)b * Hc + t];
    __syncthreads();
    if (t < 64) {
        float a = latb[t];
        const float* wp = latW + (size_t)t * 512;
        for (int k = 0; k < 512; k++) a += wp[k] * s_hn[k];
        s_lat[t] = a;
    }
    __syncthreads();
    float a = l2hb[t];
    const float* wp = l2hW + (size_t)t * 64;
#pragma unroll
    for (int k = 0; k < 64; k++) a += wp[k] * s_lat[k];
    hidden[(size_t)b * Hc + t] = a;
}

// ===================== Decoder =====================
// 128 blocks of 256 threads. Recurrence as encoder (wave-local cells).
// Projection of entering-h after publish; s_op parity dbuf; out write-through.
__global__ __launch_bounds__(256, 1) void dec_kernel(
    const float* __restrict__ x,
    const float* __restrict__ Wih, const float* __restrict__ Whh,
    const float* __restrict__ bih, const float* __restrict__ bhh,
    const float* __restrict__ outW, const float* __restrict__ outb,
    const float* __restrict__ hidden, float* __restrict__ out,
    u64* __restrict__ xch,    // [64 batches][2 halves][2 parity][64]
    int T)
{
    const int t    = threadIdx.x;
    const int lane = t & 63;
    const int w    = t >> 6;
    const int j    = lane & 31;
    const int sel  = lane >> 5;
    const int g    = blockIdx.x;
    const int half = (g >> 3) & 1;
    const int b    = ((g >> 4) << 3) | (g & 7);   // 0..63
    const int Ts   = T - 1;

    inv_caches(xch);   // drop stale L2 exchange lines from previous replay

    const int u  = half * 128 + w * 32 + j;
    const int rA = sel * Hc + u;
    const int rB = (sel + 2) * Hc + u;

    __shared__ u32   s_zh[2][64];
    __shared__ float s_op[2][256];
    __shared__ u32   s_ow[32 * 256];   // own 64 outW rows packed, keyed by t

    u32 whAo[64], whAp[64], wiA[64];
    u32 whBo[64], whBp[64], wiB[64];
    {
        const int ob = half * 64, pb2 = (half ^ 1) * 64;
        const float* wrA = Whh + (size_t)rA * Hc;
        const float* wrB = Whh + (size_t)rB * Hc;
#pragma unroll
        for (int k = 0; k < 64; k++) {
            whAo[k] = pk_rne(wrA[2*(ob+k)],  wrA[2*(ob+k)+1]);
            whBo[k] = pk_rne(wrB[2*(ob+k)],  wrB[2*(ob+k)+1]);
            whAp[k] = pk_rne(wrA[2*(pb2+k)], wrA[2*(pb2+k)+1]);
            whBp[k] = pk_rne(wrB[2*(pb2+k)], wrB[2*(pb2+k)+1]);
        }
        const float* irA = Wih + (size_t)rA * Ic;
        const float* irB = Wih + (size_t)rB * Ic;
#pragma unroll
        for (int k = 0; k < 64; k++) {
            wiA[k] = pk_rne(irA[2*k], irA[2*k+1]);
            wiB[k] = pk_rne(irB[2*k], irB[2*k+1]);
        }
    }
    const float biasA = bih[rA] + bhh[rA];
    const float biasB = bih[rB] + bhh[rB];

    {   // stage own half's 64 outW rows: thread t = row half*64+(t&63), chunk t>>6
        const float* op = outW + (size_t)(half * 64 + (t & 63)) * Hc + (size_t)(t >> 6) * 64;
#pragma unroll
        for (int k = 0; k < 32; k++)
            s_ow[k * 256 + t] = pk_rne(op[2*k], op[2*k+1]);
    }
    const float outb_r = (lane >= 32 && lane < 48) ? outb[half * 64 + w * 16 + (lane - 32)] : 0.f;

    u64* xch_self = xch + ((size_t)(b * 2 + half)) * 128;
    u64* xch_peer = xch + ((size_t)(b * 2 + (half ^ 1))) * 128;

    if (t < 64) {   // own h0 pairs
        const float* hp = hidden + (size_t)b * Hc + half * 128 + 2 * t;
        u32 v = pk_rne(hp[0], hp[1]);
        s_zh[0][t] = v; s_zh[1][t] = v;
    }
    u32 vzp_init;
    {   // peer h0 pairs, per lane
        const float* hp = hidden + (size_t)b * Hc + (half ^ 1) * 128 + 2 * lane;
        vzp_init = pk_rne(hp[0], hp[1]);
    }
    float2 xn = *(const float2*)(x + ((size_t)b * T) * Ic + 2 * lane);  // step 0
    __syncthreads();

    float c = 0.f;
    for (int s = 0; s < Ts; s++) {
        u32 vzx = pk_rne(xn.x, xn.y);
        int sn = s + 1;
        if (sn < Ts)
            xn = *(const float2*)(x + ((size_t)b * T + sn) * Ic + 2 * lane);

        u32 vzo = s_zh[s & 1][lane];
        float aA0 = biasA, aA1 = 0.f, aA2 = 0.f, aA3 = 0.f;
        float aB0 = biasB, aB1 = 0.f, aB2 = 0.f, aB3 = 0.f;
#pragma unroll
        for (int k = 0; k < 64; k += 4) {
            u32 h0 = rl(vzx, k+0), h1 = rl(vzx, k+1), h2 = rl(vzx, k+2), h3 = rl(vzx, k+3);
            aA0 = dot2acc(h0, wiA[k+0], aA0); aB0 = dot2acc(h0, wiB[k+0], aB0);
            aA1 = dot2acc(h1, wiA[k+1], aA1); aB1 = dot2acc(h1, wiB[k+1], aB1);
            aA2 = dot2acc(h2, wiA[k+2], aA2); aB2 = dot2acc(h2, wiB[k+2], aB2);
            aA3 = dot2acc(h3, wiA[k+3], aA3); aB3 = dot2acc(h3, wiB[k+3], aB3);
        }
#pragma unroll
        for (int k = 0; k < 64; k += 4) {
            u32 h0 = rl(vzo, k+0), h1 = rl(vzo, k+1), h2 = rl(vzo, k+2), h3 = rl(vzo, k+3);
            aA0 = dot2acc(h0, whAo[k+0], aA0); aB0 = dot2acc(h0, whBo[k+0], aB0);
            aA1 = dot2acc(h1, whAo[k+1], aA1); aB1 = dot2acc(h1, whBo[k+1], aB1);
            aA2 = dot2acc(h2, whAo[k+2], aA2); aB2 = dot2acc(h2, whBo[k+2], aB2);
            aA3 = dot2acc(h3, whAo[k+3], aA3); aB3 = dot2acc(h3, whBo[k+3], aB3);
        }
        u32 vzp;
        if (s > 0) {
            const u64* pslot = &xch_peer[(s & 1) * 64 + lane];
            u32x2v v = ld64_l2(pslot);
            int it = 0;
            while ((int)v[1] < s)
                v = ((++it) & 1) ? ld64_mall(pslot) : ld64_l2(pslot);
            vzp = v[0];
        } else vzp = vzp_init;
#pragma unroll
        for (int k = 0; k < 64; k += 4) {
            u32 h0 = rl(vzp, k+0), h1 = rl(vzp, k+1), h2 = rl(vzp, k+2), h3 = rl(vzp, k+3);
            aA0 = dot2acc(h0, whAp[k+0], aA0); aB0 = dot2acc(h0, whBp[k+0], aB0);
            aA1 = dot2acc(h1, whAp[k+1], aA1); aB1 = dot2acc(h1, whBp[k+1], aB1);
            aA2 = dot2acc(h2, whAp[k+2], aA2); aB2 = dot2acc(h2, whBp[k+2], aB2);
            aA3 = dot2acc(h3, whAp[k+3], aA3); aB3 = dot2acc(h3, whBp[k+3], aB3);
        }
        float aAs = (aA0 + aA1) + (aA2 + aA3);
        float aBs = (aB0 + aB1) + (aB2 + aB3);

        float f_ = __shfl(aAs, 32 + j);
        float o_ = __shfl(aBs, 32 + j);
        c = sigm(f_) * c + sigm(aAs) * tanh_f(aBs);
        float h = sigm(o_) * tanh_f(c);
        float he = __shfl(h, 2 * (lane & 15));
        float ho = __shfl(h, 2 * (lane & 15) + 1);
        u32 hp = pk_rne(he, ho);
        if (lane < 16) {   // publish ASAP (every step; peer tail needs h_Ts)
            int q = w * 16 + lane;
            s_zh[(s + 1) & 1][q] = hp;
            st64_wt(&xch_self[((s + 1) & 1) * 64 + q], hp, (u32)(s + 1));
        }

        if (s > 0) {   // projection of entering h_s -> decoded[s-1] partials
            const int ksl = t >> 6;             // wave-uniform 0..3
            const int kb  = (ksl & 1) * 32;
            u32 vplo = half ? vzp : vzo;        // global h pairs 0..63
            u32 vphi = half ? vzo : vzp;        // global h pairs 64..127
            float p0 = 0.f, p1 = 0.f;
#pragma unroll
            for (int k = 0; k < 32; k += 2) {
                u32 h0b = (ksl < 2) ? rl(vplo, kb + k)     : rl(vphi, kb + k);
                u32 h1b = (ksl < 2) ? rl(vplo, kb + k + 1) : rl(vphi, kb + k + 1);
                p0 = dot2acc(h0b, s_ow[(k)     * 256 + t], p0);
                p1 = dot2acc(h1b, s_ow[(k + 1) * 256 + t], p1);
            }
            s_op[s & 1][(t & 63) * 4 + ksl] = p0 + p1;
        }
        if (s >= 2 && lane >= 32 && lane < 48) {   // store decoded[s-2] (write-through)
            int r = w * 16 + (lane - 32);
            const float* sp = s_op[(s - 1) & 1];
            float y = outb_r + ((sp[r*4+0] + sp[r*4+1]) + (sp[r*4+2] + sp[r*4+3]));
            st32_wt(&out[((size_t)b * Ts + (s - 2)) * Ic + half * 64 + r], y);
        }
        block_sync_lds();
    }

    // tail 1: pending decoded[Ts-2]
    if (lane >= 32 && lane < 48) {
        int r = w * 16 + (lane - 32);
        const float* sp = s_op[(Ts - 1) & 1];
        float y = outb_r + ((sp[r*4+0] + sp[r*4+1]) + (sp[r*4+2] + sp[r*4+3]));
        st32_wt(&out[((size_t)b * Ts + (Ts - 2)) * Ic + half * 64 + r], y);
    }
    // tail 2: decoded[Ts-1] from h_Ts
    {
        u32 vzo2 = s_zh[Ts & 1][lane];
        const u64* pslot = &xch_peer[(Ts & 1) * 64 + lane];
        u32x2v v = ld64_l2(pslot);
        int it = 0;
        while ((int)v[1] < Ts)
            v = ((++it) & 1) ? ld64_mall(pslot) : ld64_l2(pslot);
        u32 vzp2 = v[0];
        const int ksl = t >> 6;
        const int kb  = (ksl & 1) * 32;
        u32 vplo = half ? vzp2 : vzo2;
        u32 vphi = half ? vzo2 : vzp2;
        float p0 = 0.f, p1 = 0.f;
#pragma unroll
        for (int k = 0; k < 32; k += 2) {
            u32 h0b = (ksl < 2) ? rl(vplo, kb + k)     : rl(vphi, kb + k);
            u32 h1b = (ksl < 2) ? rl(vplo, kb + k + 1) : rl(vphi, kb + k + 1);
            p0 = dot2acc(h0b, s_ow[(k)     * 256 + t], p0);
            p1 = dot2acc(h1b, s_ow[(k + 1) * 256 + t], p1);
        }
        s_op[Ts & 1][(t & 63) * 4 + ksl] = p0 + p1;
    }
    block_sync_lds();
    if (lane >= 32 && lane < 48) {
        int r = w * 16 + (lane - 32);
        const float* sp = s_op[Ts & 1];
        float y = outb_r + ((sp[r*4+0] + sp[r*4+1]) + (sp[r*4+2] + sp[r*4+3]));
        st32_wt(&out[((size_t)b * Ts + (Ts - 1)) * Ic + half * 64 + r], y);
    }
}

extern "C" void kernel_launch(void* const* d_in, const int* in_sizes, int n_in,
                              void* d_out, int out_size, void* d_ws, size_t ws_size,
                              hipStream_t stream)
{
    const float* x    = (const float*)d_in[0];
    const float* WihF = (const float*)d_in[1];
    const float* WhhF = (const float*)d_in[2];
    const float* bihF = (const float*)d_in[3];
    const float* bhhF = (const float*)d_in[4];
    const float* WihB = (const float*)d_in[5];
    const float* WhhB = (const float*)d_in[6];
    const float* bihB = (const float*)d_in[7];
    const float* bhhB = (const float*)d_in[8];
    const float* latW = (const float*)d_in[9];
    const float* latb = (const float*)d_in[10];
    const float* l2hW = (const float*)d_in[11];
    const float* l2hb = (const float*)d_in[12];
    const float* dWih = (const float*)d_in[13];
    const float* dWhh = (const float*)d_in[14];
    const float* dbih = (const float*)d_in[15];
    const float* dbhh = (const float*)d_in[16];
    const float* outW = (const float*)d_in[17];
    const float* outb = (const float*)d_in[18];

    const int T = in_sizes[0] / (64 * Ic);  // 4096

    float* ws  = (float*)d_ws;
    float* hFp = ws;                 // [64,256]
    float* hBp = ws + 16384;         // [64,256]
    float* hid = ws + 32768;         // [64,256]
    u64* encXch = (u64*)(ws + 49152);   // 128*2*2*64 = 32768 u64
    u64* decXch = encXch + 32768;       // 64*2*2*64  = 16384 u64

    // zero all tags (graph replay must restart deterministically)
    hipMemsetAsync(encXch, 0, (32768 + 16384) * sizeof(u64), stream);

    enc_kernel<<<256, 256, 0, stream>>>(x, WihF, WhhF, bihF, bhhF,
                                        WihB, WhhB, bihB, bhhB,
                                        hFp, hBp, encXch, T);
    lat_kernel<<<64, 256, 0, stream>>>(hFp, hBp, latW, latb, l2hW, l2hb, hid);
    dec_kernel<<<128, 256, 0, stream>>>(x, dWih, dWhh, dbih, dbhh,
                                        outW, outb, hid, (float*)d_out,
                                        decXch, T);
}